// Round 2
// baseline (251.657 us; speedup 1.0000x reference)
//
#include <hip/hip_runtime.h>
#include <math.h>

#define E_LEN 512
#define C_CLS 14
#define BATCH 8192
#define NSLOTS 256
#define NBLK (BATCH / 8)
#define WS_G 256    // Gram offset in ws (floats)
#define WS_WB 464   // packed bf16 w offset in ws (dwords)
#define WB_ROW 260  // dwords per wB row
#define NCH 16      // K chunks of 32 e

typedef float v4f __attribute__((ext_vector_type(4)));
typedef short s8v __attribute__((ext_vector_type(8)));  // 8 bf16 (4 VGPRs)
union APk { int i[4]; s8v s; };

// f32 pair -> packed bf16 (RNE), gfx950 VOP3
#define CVT_PK_BF16(d, a, b) \
  asm("v_cvt_pk_bf16_f32 %0, %1, %2" : "=v"(d) : "v"(a), "v"(b))

// ---- cross-lane helpers (VALU-pipe DPP) ----
template<int CTRL>
__device__ __forceinline__ float dpp_mov_f(float v) {
  return __int_as_float(__builtin_amdgcn_update_dpp(
      0, __float_as_int(v), CTRL, 0xF, 0xF, false));
}
__device__ __forceinline__ float sum16(float v) {  // row16 sum (ror 8,4,2,1)
  v += dpp_mov_f<0x128>(v);
  v += dpp_mov_f<0x124>(v);
  v += dpp_mov_f<0x122>(v);
  v += dpp_mov_f<0x121>(v);
  return v;
}
// lane31 = sum(lanes 0..31), lane63 = sum(lanes 32..63)
__device__ __forceinline__ float hsum32(float v) {
  v = sum16(v);
  v += dpp_mov_f<0x142>(v);  // row_bcast15
  return v;
}
__device__ __forceinline__ float wsum64(float v) {
  v = sum16(v);
  v += dpp_mov_f<0x142>(v);
  v += dpp_mov_f<0x143>(v);
  return v;
}
template<int PAT>
__device__ __forceinline__ float swz_f(float v) {  // 32-lane-group swizzle
  return __int_as_float(__builtin_amdgcn_ds_swizzle(__float_as_int(v), PAT));
}
__device__ __forceinline__ float shfl_x32(float v) {
  return __shfl_xor(v, 32, 64);
}
__device__ __forceinline__ float softplus_f(float v) {
  return fmaxf(v, 0.f) + __logf(1.f + __expf(-fabsf(v)));
}

// ---- prep (1 block): zero slots, Gram G=w^T w (fp32), pack w -> bf16 rows ----
__global__ void MID_LOSS_prep(const float* __restrict__ w,
                              float* __restrict__ wsf) {
  __shared__ float wl[E_LEN * C_CLS];
  const int tid = threadIdx.x;
#pragma unroll
  for (int i = 0; i < 7; ++i)
    ((float4*)wl)[tid + i * 256] = ((const float4*)w)[tid + i * 256];
  wsf[tid] = 0.f;  // slots
  __syncthreads();
  if (tid < 196) {
    const int p = tid / 14, n = tid - p * 14;
    float g = 0.f;
    for (int e = 0; e < E_LEN; ++e)
      g = fmaf(wl[e * 14 + p], wl[e * 14 + n], g);
    wsf[WS_G + tid] = g;
  }
  // wB[c][e] bf16, c padded to 16 (zeros), row stride WB_ROW dwords
  unsigned int* wsu = (unsigned int*)wsf;
  for (int i = tid; i < 4096; i += 256) {
    const int c = i >> 8;        // 0..15
    const int ep = i & 255;      // e-pair
    const int e = ep * 2;
    const float v0 = (c < 14) ? wl[e * 14 + c] : 0.f;
    const float v1 = (c < 14) ? wl[(e + 1) * 14 + c] : 0.f;
    int d;
    CVT_PK_BF16(d, v0, v1);
    wsu[WS_WB + c * WB_ROW + ep] = (unsigned int)d;
  }
}

// ---- main: 1 block = 8 samples; DIRECT strided global->register x loads
//      (no LDS staging of x, no asm fences), 2-deep register prefetch,
//      MFMA core. LDS only holds bf16 w + Gram -> 8 blocks/CU ----
__global__ __launch_bounds__(256, 8)
void MID_LOSS_main(const float* __restrict__ x, const int* __restrict__ y,
                   const float* __restrict__ wsf, float* __restrict__ slots) {
  __shared__ unsigned int wB_l[16 * WB_ROW];  // 16.6 KB bf16 w
  __shared__ float G_l[196];
  __shared__ float dots_l[4][2][16];
  __shared__ float P_l[4][2][16];

  const int tid = threadIdx.x;
  const int lane = tid & 63;
  const int wid = tid >> 6;
  const unsigned int* wsu = (const unsigned int*)wsf;

  // stage packed w + Gram once per block (one barrier total)
  for (int i = tid; i < 16 * WB_ROW; i += 256) wB_l[i] = wsu[WS_WB + i];
  if (tid < 196) G_l[tid] = wsf[WS_G + tid];
  __syncthreads();

  // fragment geometry: A row = (sample, m), k-slice kg = lane>>4
  const int row = lane & 15;
  const int kg = lane >> 4;
  const int m = row & 7;
  const int b0 = blockIdx.x * 8 + wid * 2;  // this wave's 2 samples
  // per-lane x base: sample (b0 + slot), k-group kg, feature m
  const float* xl = x + (size_t)b0 * 4096 + (row >> 3) * 4096 + kg * 64 + m;
  const unsigned int* wrow = wB_l + row * WB_ROW;

  // hoist the y read (its latency hides under the K-loop)
  const int yv = (lane < 28) ? y[b0 * 14 + lane] : 0;

  v4f acc = {0.f, 0.f, 0.f, 0.f};   // dot C-tile
  v4f acc2 = {0.f, 0.f, 0.f, 0.f};  // Gram C-tile (A*A^T)
  float q = 0.f;                    // fp32 sum u^2 (this lane's slice)

  float u[2][8];  // 2-deep chunk prefetch; all indices static (full unroll)
#pragma unroll
  for (int j = 0; j < 8; ++j) u[0][j] = xl[j * 8];

#pragma unroll
  for (int ch = 0; ch < NCH; ++ch) {
    const int cur = ch & 1;
    // prefetch next chunk's 8 strided dwords straight to registers
    if (ch < NCH - 1) {
#pragma unroll
      for (int j = 0; j < 8; ++j) u[cur ^ 1][j] = xl[(ch + 1) * 256 + j * 8];
    }
    const s8v bfrag = *(const s8v*)(wrow + ch * 16 + kg * 4);
#pragma unroll
    for (int j = 0; j < 8; ++j) q = fmaf(u[cur][j], u[cur][j], q);
    APk a;
#pragma unroll
    for (int jj = 0; jj < 4; ++jj)
      CVT_PK_BF16(a.i[jj], u[cur][2 * jj], u[cur][2 * jj + 1]);

    acc = __builtin_amdgcn_mfma_f32_16x16x32_bf16(a.s, bfrag, acc, 0, 0, 0);
    acc2 = __builtin_amdgcn_mfma_f32_16x16x32_bf16(a.s, a.s, acc2, 0, 0, 0);
  }

  // ---- stage P mask for the wave's 2 samples (same-wave, no barrier) ----
  if (lane < 28) {
    const int s = (lane >= 14) ? 1 : 0;
    P_l[wid][s][lane - s * 14] = (yv == 1) ? 1.f : 0.f;
  }

  // ---- dot tail: max over m (C layout: col=lane&15, row=kg*4+reg) ----
  float dmax = fmaxf(fmaxf(acc[0], acc[1]), fmaxf(acc[2], acc[3]));
  dmax = fmaxf(dmax, swz_f<0x401F>(dmax));  // xor16: combine kg pairs
  if ((lane & 16) == 0 && (lane & 15) < 14)
    dots_l[wid][lane >> 5][lane & 15] = dmax;

  // ---- Gram tail: per-sample 8x8 block sum (for l1) ----
  const float loc2 = acc2[0] + acc2[1] + acc2[2] + acc2[3];
  const bool validb = (((lane & 15) < 8) == (lane < 32));
  float s2v = validb ? loc2 : 0.f;
  float q2 = q + shfl_x32(q);
  float qv = validb ? q2 : 0.f;

  asm volatile("s_waitcnt lgkmcnt(0)" ::: "memory");  // dots/P visible in-wave

  // ---- pair phase: lanes 0-31 do b0's 196 pairs, lanes 32-63 do b1's ----
  const int half = lane >> 5;
  const int hl = lane & 31;
  const float* dp = dots_l[wid][half];
  const float* Pp = P_l[wid][half];
  float S = 0.f, Gc = 0.f;
#pragma unroll
  for (int r = 0; r < 7; ++r) {
    const int tt = r * 28 + hl;
    if (hl < 28) {
      const int p = (tt * 2341) >> 15;  // tt/14, exact for tt<196
      const int n = tt - p * 14;
      const float Ppv = Pp[p], Pnv = Pp[n];
      S += Ppv * (1.f - Pnv) * softplus_f(dp[n] - dp[p]);
      Gc = fmaf(Ppv * Pnv, G_l[tt], Gc);
    }
  }
  float npv = (hl < 14) ? Pp[hl] : 0.f;
  float w2v = (hl < 14) ? Pp[hl] * G_l[hl * 15] : 0.f;  // P[c]*G[c][c]

  // ---- six half-reductions: lane31 = b0 totals, lane63 = b1 totals ----
  S = hsum32(S);
  Gc = hsum32(Gc);
  s2v = hsum32(s2v);
  qv = hsum32(qv);
  npv = hsum32(npv);
  w2v = hsum32(w2v);

  float loss = 0.f;
  if ((lane & 31) == 31) {
    const float npos = npv;
    const float base = S / npos;  // nneg>=1 guaranteed (y[:,-1]=0)
    const float tv =
        (npos > 1.5f) ? (w2v - Gc / npos) / (npos - 1.f) : 0.f;
    // l1 = sum_e sig2 (var >= 0) = (sum u^2 - (1/8) sum_e t^2)/7
    const float l1 = (qv - s2v * 0.125f) * (1.f / 7.f);
    loss = 1.4f * (1.f + tv) * base + 0.6f * l1;  // 2*((1-b)(1+tv)base + b*l1)
  }
  loss += shfl_x32(loss);  // lane31 = b0+b1
  if (lane == 31) atomicAdd(&slots[blockIdx.x & (NSLOTS - 1)], loss);
}

// ---- finalize (1 wave): sum the 256 slots -> out[0] ----
__global__ void MID_LOSS_fin(const float* __restrict__ wsf,
                             float* __restrict__ out) {
  const int tid = threadIdx.x;  // 64 threads
  float s = wsf[tid] + wsf[tid + 64] + wsf[tid + 128] + wsf[tid + 192];
  s = wsum64(s);
  if (tid == 63) out[0] = s * (1.f / (float)BATCH);
}

extern "C" void kernel_launch(void* const* d_in, const int* in_sizes, int n_in,
                              void* d_out, int out_size, void* d_ws, size_t ws_size,
                              hipStream_t stream) {
  const float* x = (const float*)d_in[0];
  const int* y = (const int*)d_in[1];
  const float* w = (const float*)d_in[2];
  float* out = (float*)d_out;
  float* wsf = (float*)d_ws;

  MID_LOSS_prep<<<1, 256, 0, stream>>>(w, wsf);
  MID_LOSS_main<<<NBLK, 256, 0, stream>>>(x, y, wsf, wsf);
  MID_LOSS_fin<<<1, 64, 0, stream>>>(wsf, out);
}

// Round 3
// 217.926 us; speedup vs baseline: 1.1548x; 1.1548x over previous
//
#include <hip/hip_runtime.h>
#include <math.h>

#define E_LEN 512
#define C_CLS 14
#define BATCH 8192
#define NSLOTS 256
#define NBLK (BATCH / 8)
#define WS_G 256    // Gram offset in ws (floats)
#define WS_WB 464   // packed bf16 w offset in ws (dwords)
#define WB_ROW 260  // dwords per wB row
#define NCH 16      // K chunks of 32 e

typedef float v4f __attribute__((ext_vector_type(4)));
typedef short s8v __attribute__((ext_vector_type(8)));  // 8 bf16 (4 VGPRs)
union APk { int i[4]; s8v s; };

// f32 pair -> packed bf16 (RNE), gfx950 VOP3
#define CVT_PK_BF16(d, a, b) \
  asm("v_cvt_pk_bf16_f32 %0, %1, %2" : "=v"(d) : "v"(a), "v"(b))

// ---- cross-lane helpers (VALU-pipe DPP) ----
template<int CTRL>
__device__ __forceinline__ float dpp_mov_f(float v) {
  return __int_as_float(__builtin_amdgcn_update_dpp(
      0, __float_as_int(v), CTRL, 0xF, 0xF, false));
}
__device__ __forceinline__ float sum16(float v) {  // row16 sum (ror 8,4,2,1)
  v += dpp_mov_f<0x128>(v);
  v += dpp_mov_f<0x124>(v);
  v += dpp_mov_f<0x122>(v);
  v += dpp_mov_f<0x121>(v);
  return v;
}
// lane31 = sum(lanes 0..31), lane63 = sum(lanes 32..63)
__device__ __forceinline__ float hsum32(float v) {
  v = sum16(v);
  v += dpp_mov_f<0x142>(v);  // row_bcast15
  return v;
}
__device__ __forceinline__ float wsum64(float v) {
  v = sum16(v);
  v += dpp_mov_f<0x142>(v);
  v += dpp_mov_f<0x143>(v);
  return v;
}
template<int PAT>
__device__ __forceinline__ float swz_f(float v) {  // 32-lane-group swizzle
  return __int_as_float(__builtin_amdgcn_ds_swizzle(__float_as_int(v), PAT));
}
__device__ __forceinline__ float shfl_x32(float v) {
  return __shfl_xor(v, 32, 64);
}
__device__ __forceinline__ float softplus_f(float v) {
  return fmaxf(v, 0.f) + __logf(1.f + __expf(-fabsf(v)));
}

// ---- prep (1 block): zero slots, Gram G=w^T w (fp32), pack w -> bf16 rows ----
__global__ void MID_LOSS_prep(const float* __restrict__ w,
                              float* __restrict__ wsf) {
  __shared__ float wl[E_LEN * C_CLS];
  const int tid = threadIdx.x;
#pragma unroll
  for (int i = 0; i < 7; ++i)
    ((float4*)wl)[tid + i * 256] = ((const float4*)w)[tid + i * 256];
  wsf[tid] = 0.f;  // slots
  __syncthreads();
  if (tid < 196) {
    const int p = tid / 14, n = tid - p * 14;
    float g = 0.f;
    for (int e = 0; e < E_LEN; ++e)
      g = fmaf(wl[e * 14 + p], wl[e * 14 + n], g);
    wsf[WS_G + tid] = g;
  }
  // wB[c][e] bf16, c padded to 16 (zeros), row stride WB_ROW dwords
  unsigned int* wsu = (unsigned int*)wsf;
  for (int i = tid; i < 4096; i += 256) {
    const int c = i >> 8;        // 0..15
    const int ep = i & 255;      // e-pair
    const int e = ep * 2;
    const float v0 = (c < 14) ? wl[e * 14 + c] : 0.f;
    const float v1 = (c < 14) ? wl[(e + 1) * 14 + c] : 0.f;
    int d;
    CVT_PK_BF16(d, v0, v1);
    wsu[WS_WB + c * WB_ROW + ep] = (unsigned int)d;
  }
}

// ---- main: 1 block = 8 samples; DIRECT strided global->register x loads
//      (no LDS staging of x), 2-deep register prefetch, MFMA core.
//      launch_bounds(256,4): 128-VGPR budget -> NO SPILLS (round-2 lesson:
//      (256,8) capped at 64 VGPR and spilled 89 MB to scratch) ----
__global__ __launch_bounds__(256, 4)
void MID_LOSS_main(const float* __restrict__ x, const int* __restrict__ y,
                   const float* __restrict__ wsf, float* __restrict__ slots) {
  __shared__ unsigned int wB_l[16 * WB_ROW];  // 16.6 KB bf16 w
  __shared__ float G_l[196];
  __shared__ float dots_l[4][2][16];
  __shared__ float P_l[4][2][16];

  const int tid = threadIdx.x;
  const int lane = tid & 63;
  const int wid = tid >> 6;
  const unsigned int* wsu = (const unsigned int*)wsf;

  // stage packed w + Gram once per block (one barrier total)
  for (int i = tid; i < 16 * WB_ROW; i += 256) wB_l[i] = wsu[WS_WB + i];
  if (tid < 196) G_l[tid] = wsf[WS_G + tid];
  __syncthreads();

  // fragment geometry: A row = (sample, m), k-slice kg = lane>>4
  const int row = lane & 15;
  const int kg = lane >> 4;
  const int m = row & 7;
  const int b0 = blockIdx.x * 8 + wid * 2;  // this wave's 2 samples
  // per-lane x base: sample (b0 + slot), k-group kg, feature m
  const float* xl = x + (size_t)b0 * 4096 + (row >> 3) * 4096 + kg * 64 + m;
  const unsigned int* wrow = wB_l + row * WB_ROW;

  // hoist the y read (its latency hides under the K-loop)
  const int yv = (lane < 28) ? y[b0 * 14 + lane] : 0;

  v4f acc = {0.f, 0.f, 0.f, 0.f};   // dot C-tile
  v4f acc2 = {0.f, 0.f, 0.f, 0.f};  // Gram C-tile (A*A^T)
  float q = 0.f;                    // fp32 sum u^2 (this lane's slice)

  float u[2][8];  // 2-deep chunk prefetch; all indices static (full unroll)
#pragma unroll
  for (int j = 0; j < 8; ++j) u[0][j] = xl[j * 8];

#pragma unroll
  for (int ch = 0; ch < NCH; ++ch) {
    const int cur = ch & 1;
    // prefetch next chunk's 8 strided dwords straight to registers
    if (ch < NCH - 1) {
#pragma unroll
      for (int j = 0; j < 8; ++j) u[cur ^ 1][j] = xl[(ch + 1) * 256 + j * 8];
    }
    const s8v bfrag = *(const s8v*)(wrow + ch * 16 + kg * 4);
#pragma unroll
    for (int j = 0; j < 8; ++j) q = fmaf(u[cur][j], u[cur][j], q);
    APk a;
#pragma unroll
    for (int jj = 0; jj < 4; ++jj)
      CVT_PK_BF16(a.i[jj], u[cur][2 * jj], u[cur][2 * jj + 1]);

    acc = __builtin_amdgcn_mfma_f32_16x16x32_bf16(a.s, bfrag, acc, 0, 0, 0);
    acc2 = __builtin_amdgcn_mfma_f32_16x16x32_bf16(a.s, a.s, acc2, 0, 0, 0);
  }

  // ---- stage P mask for the wave's 2 samples (same-wave, no barrier) ----
  if (lane < 28) {
    const int s = (lane >= 14) ? 1 : 0;
    P_l[wid][s][lane - s * 14] = (yv == 1) ? 1.f : 0.f;
  }

  // ---- dot tail: max over m (C layout: col=lane&15, row=kg*4+reg) ----
  float dmax = fmaxf(fmaxf(acc[0], acc[1]), fmaxf(acc[2], acc[3]));
  dmax = fmaxf(dmax, swz_f<0x401F>(dmax));  // xor16: combine kg pairs
  if ((lane & 16) == 0 && (lane & 15) < 14)
    dots_l[wid][lane >> 5][lane & 15] = dmax;

  // ---- Gram tail: per-sample 8x8 block sum (for l1) ----
  const float loc2 = acc2[0] + acc2[1] + acc2[2] + acc2[3];
  const bool validb = (((lane & 15) < 8) == (lane < 32));
  float s2v = validb ? loc2 : 0.f;
  float q2 = q + shfl_x32(q);
  float qv = validb ? q2 : 0.f;

  asm volatile("s_waitcnt lgkmcnt(0)" ::: "memory");  // dots/P visible in-wave

  // ---- pair phase: lanes 0-31 do b0's 196 pairs, lanes 32-63 do b1's ----
  const int half = lane >> 5;
  const int hl = lane & 31;
  const float* dp = dots_l[wid][half];
  const float* Pp = P_l[wid][half];
  float S = 0.f, Gc = 0.f;
#pragma unroll
  for (int r = 0; r < 7; ++r) {
    const int tt = r * 28 + hl;
    if (hl < 28) {
      const int p = (tt * 2341) >> 15;  // tt/14, exact for tt<196
      const int n = tt - p * 14;
      const float Ppv = Pp[p], Pnv = Pp[n];
      S += Ppv * (1.f - Pnv) * softplus_f(dp[n] - dp[p]);
      Gc = fmaf(Ppv * Pnv, G_l[tt], Gc);
    }
  }
  float npv = (hl < 14) ? Pp[hl] : 0.f;
  float w2v = (hl < 14) ? Pp[hl] * G_l[hl * 15] : 0.f;  // P[c]*G[c][c]

  // ---- six half-reductions: lane31 = b0 totals, lane63 = b1 totals ----
  S = hsum32(S);
  Gc = hsum32(Gc);
  s2v = hsum32(s2v);
  qv = hsum32(qv);
  npv = hsum32(npv);
  w2v = hsum32(w2v);

  float loss = 0.f;
  if ((lane & 31) == 31) {
    const float npos = npv;
    const float base = S / npos;  // nneg>=1 guaranteed (y[:,-1]=0)
    const float tv =
        (npos > 1.5f) ? (w2v - Gc / npos) / (npos - 1.f) : 0.f;
    // l1 = sum_e sig2 (var >= 0) = (sum u^2 - (1/8) sum_e t^2)/7
    const float l1 = (qv - s2v * 0.125f) * (1.f / 7.f);
    loss = 1.4f * (1.f + tv) * base + 0.6f * l1;  // 2*((1-b)(1+tv)base + b*l1)
  }
  loss += shfl_x32(loss);  // lane31 = b0+b1
  if (lane == 31) atomicAdd(&slots[blockIdx.x & (NSLOTS - 1)], loss);
}

// ---- finalize (1 wave): sum the 256 slots -> out[0] ----
__global__ void MID_LOSS_fin(const float* __restrict__ wsf,
                             float* __restrict__ out) {
  const int tid = threadIdx.x;  // 64 threads
  float s = wsf[tid] + wsf[tid + 64] + wsf[tid + 128] + wsf[tid + 192];
  s = wsum64(s);
  if (tid == 63) out[0] = s * (1.f / (float)BATCH);
}

extern "C" void kernel_launch(void* const* d_in, const int* in_sizes, int n_in,
                              void* d_out, int out_size, void* d_ws, size_t ws_size,
                              hipStream_t stream) {
  const float* x = (const float*)d_in[0];
  const int* y = (const int*)d_in[1];
  const float* w = (const float*)d_in[2];
  float* out = (float*)d_out;
  float* wsf = (float*)d_ws;

  MID_LOSS_prep<<<1, 256, 0, stream>>>(w, wsf);
  MID_LOSS_main<<<NBLK, 256, 0, stream>>>(x, y, wsf, wsf);
  MID_LOSS_fin<<<1, 64, 0, stream>>>(wsf, out);
}